// Round 3
// baseline (336.596 us; speedup 1.0000x reference)
//
#include <hip/hip_runtime.h>
#include <hip/hip_bf16.h>

// TT-matrix embedding: vocab 50*60*60, embed 8*8*8, rank 16.
//
// Bucketed scheme (round-3): 131072 tokens / 3000 (i1,i2) pairs = ~44 tokens/pair.
//   1. zero counts
//   2. histogram tokens by pair = id/60 (atomicAdd)
//   3. exclusive scan (1 block) -> bases, cursors
//   4. scatter token indices into perm[] by bucket
//   5. embed: one block (4 waves) per bucket. Each wave computes the bucket's
//      t12[ab][0:16] tile in REGISTERS (g1,g2 from L2-hot 25KB/1.9MB tables),
//      then loops over the bucket's tokens: i3 = id%60, broadcast g3 loads from
//      the 30KB L1-resident c3, 128 FMA/lane, 2 coalesced float4 stores.
// This removes round-2's 536 MB of random t12-table reads (the latency-bound
// bottleneck: embed2 ran ~320us at ~2.5 TB/s effective). HBM traffic is now
// ~268 MB of coalesced writes + ~1 MB binning.

#define M2M3 3600u
#define M3 60u
#define NPAIR 3000
#define EMB_BLOCK 256

__global__ __launch_bounds__(256) void tt_zero_kernel(int* __restrict__ counts) {
    const int i = blockIdx.x * blockDim.x + threadIdx.x;
    if (i < NPAIR) counts[i] = 0;
}

__global__ __launch_bounds__(256) void tt_hist_kernel(
    const int* __restrict__ x, int* __restrict__ counts, int T)
{
    const int u = blockIdx.x * blockDim.x + threadIdx.x;
    if (u >= T) return;
    const unsigned pair = (unsigned)x[u] / M3;   // i1*60 + i2
    atomicAdd(&counts[pair], 1);
}

__global__ __launch_bounds__(1024) void tt_scan_kernel(
    const int* __restrict__ counts, int* __restrict__ bases, int* __restrict__ cursors)
{
    __shared__ int s[1024];
    const int t = threadIdx.x;
    const int c0 = t * 3;                         // covers 0..3071 >= 3000
    const int v0 = (c0     < NPAIR) ? counts[c0]     : 0;
    const int v1 = (c0 + 1 < NPAIR) ? counts[c0 + 1] : 0;
    const int v2 = (c0 + 2 < NPAIR) ? counts[c0 + 2] : 0;
    const int mysum = v0 + v1 + v2;
    s[t] = mysum;
    __syncthreads();
    // Hillis-Steele inclusive scan over 1024 chunk sums
    for (int off = 1; off < 1024; off <<= 1) {
        int val = (t >= off) ? s[t - off] : 0;
        __syncthreads();
        if (t >= off) s[t] += val;
        __syncthreads();
    }
    int excl = s[t] - mysum;                      // exclusive prefix of this chunk
    if (c0 < NPAIR)     { bases[c0]     = excl; cursors[c0]     = excl; }
    excl += v0;
    if (c0 + 1 < NPAIR) { bases[c0 + 1] = excl; cursors[c0 + 1] = excl; }
    excl += v1;
    if (c0 + 2 < NPAIR) { bases[c0 + 2] = excl; cursors[c0 + 2] = excl; }
}

__global__ __launch_bounds__(256) void tt_scatter_kernel(
    const int* __restrict__ x, int* __restrict__ cursors,
    int* __restrict__ perm, int T)
{
    const int u = blockIdx.x * blockDim.x + threadIdx.x;
    if (u >= T) return;
    const unsigned pair = (unsigned)x[u] / M3;
    const int pos = atomicAdd(&cursors[pair], 1);
    perm[pos] = u;
}

__global__ __launch_bounds__(256) void tt_bucket_embed_kernel(
    const int* __restrict__ x,      // [T]
    const float* __restrict__ c1,   // [50][8][16]
    const float* __restrict__ c2,   // [60][16][8][16]
    const float* __restrict__ c3,   // [60][16][8]
    const int* __restrict__ bases,
    const int* __restrict__ counts,
    const int* __restrict__ perm,
    float* __restrict__ out)        // [T][512]
{
    const int pair = blockIdx.x;
    const int i1 = pair / 60;
    const int i2 = pair - i1 * 60;
    const int wave = threadIdx.x >> 6;
    const int lane = threadIdx.x & 63;
    const int a = lane >> 3;
    const int b = lane & 7;

    const int base  = bases[pair];
    const int count = counts[pair];
    if (count == 0) return;

    // t12[ab][s] = sum_r g1[a][r] * g2[r][b][s]  -- once per wave, in registers
    const float* __restrict__ g1 = c1 + i1 * 128 + a * 16;
    const float* __restrict__ g2 = c2 + i2 * 2048 + b * 16;
    float t12[16];
#pragma unroll
    for (int s = 0; s < 16; ++s) t12[s] = 0.f;
#pragma unroll
    for (int r = 0; r < 16; ++r) {
        const float a1 = g1[r];
        const float4* row = (const float4*)(g2 + r * 128);
#pragma unroll
        for (int q = 0; q < 4; ++q) {
            const float4 v = row[q];
            t12[q * 4 + 0] = fmaf(a1, v.x, t12[q * 4 + 0]);
            t12[q * 4 + 1] = fmaf(a1, v.y, t12[q * 4 + 1]);
            t12[q * 4 + 2] = fmaf(a1, v.z, t12[q * 4 + 2]);
            t12[q * 4 + 3] = fmaf(a1, v.w, t12[q * 4 + 3]);
        }
    }

    // token loop: 4 waves of the block split the bucket
    for (int k = wave; k < count; k += 4) {
        const int u = __builtin_amdgcn_readfirstlane(perm[base + k]);
        const unsigned id = __builtin_amdgcn_readfirstlane((unsigned)x[u]);
        const unsigned i3 = id % M3;               // id%3600%60 == id%60
        const float4* __restrict__ g3 = (const float4*)(c3 + i3 * 128u);

        float o[8];
#pragma unroll
        for (int c = 0; c < 8; ++c) o[c] = 0.f;
#pragma unroll
        for (int s = 0; s < 16; ++s) {
            const float ts = t12[s];
            const float4 w0 = g3[s * 2 + 0];
            const float4 w1 = g3[s * 2 + 1];
            o[0] = fmaf(ts, w0.x, o[0]);
            o[1] = fmaf(ts, w0.y, o[1]);
            o[2] = fmaf(ts, w0.z, o[2]);
            o[3] = fmaf(ts, w0.w, o[3]);
            o[4] = fmaf(ts, w1.x, o[4]);
            o[5] = fmaf(ts, w1.y, o[5]);
            o[6] = fmaf(ts, w1.z, o[6]);
            o[7] = fmaf(ts, w1.w, o[7]);
        }
        float4* dst = (float4*)(out + (size_t)u * 512 + lane * 8);
        dst[0] = make_float4(o[0], o[1], o[2], o[3]);
        dst[1] = make_float4(o[4], o[5], o[6], o[7]);
    }
}

// ---- fallback (round-1 single-pass kernel) if d_ws is too small ----
__global__ __launch_bounds__(256) void tt_embed_kernel(
    const int* __restrict__ x, const float* __restrict__ c1,
    const float* __restrict__ c2, const float* __restrict__ c3,
    float* __restrict__ out, int T)
{
    const int u    = (int)((blockIdx.x * blockDim.x + threadIdx.x) >> 6);
    const int lane = threadIdx.x & 63;
    if (u >= T) return;
    const int a = lane >> 3, b = lane & 7;
    const unsigned id  = (unsigned)x[u];
    const unsigned i1  = id / M2M3;
    const unsigned rem = id - i1 * M2M3;
    const unsigned i2  = rem / M3;
    const unsigned i3  = rem - i2 * M3;
    const float4* g1 = (const float4*)(c1 + i1 * 128u + a * 16);
    const float*  g2 = c2 + i2 * 2048u + b * 16;
    const float4* g3 = (const float4*)(c3 + i3 * 128u);
    float4 a1v[4];
#pragma unroll
    for (int q = 0; q < 4; ++q) a1v[q] = g1[q];
    const float* a1f = (const float*)a1v;
    float t12[16];
#pragma unroll
    for (int s = 0; s < 16; ++s) t12[s] = 0.f;
#pragma unroll
    for (int r = 0; r < 16; ++r) {
        const float a1 = a1f[r];
        const float4* row = (const float4*)(g2 + r * 128);
#pragma unroll
        for (int q = 0; q < 4; ++q) {
            const float4 v = row[q];
            t12[q*4+0] = fmaf(a1, v.x, t12[q*4+0]);
            t12[q*4+1] = fmaf(a1, v.y, t12[q*4+1]);
            t12[q*4+2] = fmaf(a1, v.z, t12[q*4+2]);
            t12[q*4+3] = fmaf(a1, v.w, t12[q*4+3]);
        }
    }
    float o[8];
#pragma unroll
    for (int c = 0; c < 8; ++c) o[c] = 0.f;
#pragma unroll
    for (int s = 0; s < 16; ++s) {
        const float ts = t12[s];
        const float4 w0 = g3[s*2+0];
        const float4 w1 = g3[s*2+1];
        o[0]=fmaf(ts,w0.x,o[0]); o[1]=fmaf(ts,w0.y,o[1]);
        o[2]=fmaf(ts,w0.z,o[2]); o[3]=fmaf(ts,w0.w,o[3]);
        o[4]=fmaf(ts,w1.x,o[4]); o[5]=fmaf(ts,w1.y,o[5]);
        o[6]=fmaf(ts,w1.z,o[6]); o[7]=fmaf(ts,w1.w,o[7]);
    }
    float4* dst = (float4*)(out + (size_t)u * 512 + lane * 8);
    dst[0] = make_float4(o[0], o[1], o[2], o[3]);
    dst[1] = make_float4(o[4], o[5], o[6], o[7]);
}

extern "C" void kernel_launch(void* const* d_in, const int* in_sizes, int n_in,
                              void* d_out, int out_size, void* d_ws, size_t ws_size,
                              hipStream_t stream) {
    const int*   x  = (const int*)d_in[0];
    const float* c1 = (const float*)d_in[1];
    const float* c2 = (const float*)d_in[2];
    const float* c3 = (const float*)d_in[3];
    float* out = (float*)d_out;

    const int T = in_sizes[0];                   // 131072 tokens

    // workspace layout: counts[3000] | bases[3000] | cursors[3000] | perm[T]
    const size_t need = (size_t)(3 * NPAIR + T) * sizeof(int);

    if (ws_size >= need) {
        int* counts  = (int*)d_ws;
        int* bases   = counts + NPAIR;
        int* cursors = bases + NPAIR;
        int* perm    = cursors + NPAIR;

        tt_zero_kernel<<<(NPAIR + 255) / 256, 256, 0, stream>>>(counts);
        tt_hist_kernel<<<(T + 255) / 256, 256, 0, stream>>>(x, counts, T);
        tt_scan_kernel<<<1, 1024, 0, stream>>>(counts, bases, cursors);
        tt_scatter_kernel<<<(T + 255) / 256, 256, 0, stream>>>(x, cursors, perm, T);
        tt_bucket_embed_kernel<<<NPAIR, EMB_BLOCK, 0, stream>>>(
            x, c1, c2, c3, bases, counts, perm, out);
    } else {
        const int blocks = (T + 3) / 4;
        tt_embed_kernel<<<blocks, 256, 0, stream>>>(x, c1, c2, c3, out, T);
    }
}